// Round 6
// baseline (499.873 us; speedup 1.0000x reference)
//
#include <hip/hip_runtime.h>

typedef __bf16 bf16_t;
typedef __bf16 bf16x4 __attribute__((ext_vector_type(4)));
typedef __bf16 bf16x8 __attribute__((ext_vector_type(8)));
typedef float  f32x4  __attribute__((ext_vector_type(4)));

#define NPIX 2048
#define NS   64
#define NK   8
#define NSAMP (NPIX*NS)          // 131072
#define NROWS (NSAMP*NK)         // 1048576
#define TROWS 64
#define NTILES (NROWS/TROWS)     // 16384
#define XSTR 104                 // 96 cols + 8 pad (bf16)
#define HSTR 136                 // 128 cols + 8 pad (bf16)

// packed-weight fragment bases (in bf16x8 units)
#define PK_W0 0
#define PK_W1 1536               // W0p: 8 ntiles * 3 ksteps * 64
#define PK_W2 3584               // W1p: 8*4*64 = 2048
#define PK_WA 5632               // W2p: 2048
#define PK_WR 6656               // Wa0p: 4*4*64 = 1024
#define PK_TOT 7680              // Wr0p: 1024 -> total 61440 bf16 = 122880 B

#define WS_AR_BYTES 122880       // float4 per sample after packed weights

// ---------------------------------------------------------------------------
// Pack W (row-major [KD,ND] fp32) into MFMA B-fragment order, bf16:
// elem e = ((t*KS + s)*64 + l)*8 + j  holds  W[s*32 + (l>>4)*8 + j][t*16 + (l&15)]
// ---------------------------------------------------------------------------
__global__ void pack_weights(const float* __restrict__ W0, const float* __restrict__ W1,
                             const float* __restrict__ W2, const float* __restrict__ Wa0,
                             const float* __restrict__ Wr0, bf16_t* __restrict__ dst0) {
  int tid = blockIdx.x * blockDim.x + threadIdx.x;
  if (tid >= PK_TOT * 8) return;
  const float* src; bf16_t* dst; int e, KD, ND, KS;
  if (tid < 12288)      { src = W0;  dst = dst0;         e = tid;         KD = 88;  ND = 128; KS = 3; }
  else if (tid < 28672) { src = W1;  dst = dst0 + 12288; e = tid - 12288; KD = 128; ND = 128; KS = 4; }
  else if (tid < 45056) { src = W2;  dst = dst0 + 28672; e = tid - 28672; KD = 128; ND = 128; KS = 4; }
  else if (tid < 53248) { src = Wa0; dst = dst0 + 45056; e = tid - 45056; KD = 128; ND = 64;  KS = 4; }
  else                  { src = Wr0; dst = dst0 + 53248; e = tid - 53248; KD = 128; ND = 64;  KS = 4; }
  int j = e & 7, l = (e >> 3) & 63, f = e >> 9;
  int s = f % KS, t = f / KS;
  int row = s * 32 + (l >> 4) * 8 + j;
  int col = t * 16 + (l & 15);
  float v = (row < KD) ? src[row * ND + col] : 0.f;
  dst[e] = (bf16_t)v;
}

__device__ __forceinline__ float lrelu(float v) { return fmaxf(v, 0.1f * v); }
__device__ __forceinline__ float sigmoidf(float x) { return 1.f / (1.f + __expf(-x)); }

// ---------------------------------------------------------------------------
// Main fused kernel. Block: 512 thr (8 waves). ROW-SPLIT wave mapping
// (round-1 verified): wave = (rh = wid>>2 owns rows rh*32..+31,
// cp = wid&3 owns col-tiles cp*2, cp*2+1). Each A-fragment read feeds 2
// MFMAs (halves LDS read instrs vs the col-split round-4/5 layout).
// Register diet for 2 blocks/CU: only w1f/w2f persistent (64 VGPR);
// w0f + head frags loaded per tile from global wpack (L1-resident; LICM
// defeated by a tile-dependent zero offset). Finals = one 16x16x32 MFMA
// on wave 0 (shuffles are LDS-pipe ops on CDNA — round-5 lesson).
// ---------------------------------------------------------------------------
__global__ __launch_bounds__(512, 4)
void nerf_main(const float* __restrict__ map_xyz, const float* __restrict__ map_feat,
               const int* __restrict__ ind, const float* __restrict__ sample_xyz,
               const float* __restrict__ b0g, const float* __restrict__ b1g,
               const float* __restrict__ b2g, const float* __restrict__ ba0g,
               const float* __restrict__ wa1g, const float* __restrict__ ba1g,
               const float* __restrict__ br0g, const float* __restrict__ wr1g,
               const float* __restrict__ br1g, const bf16_t* __restrict__ wpack,
               float* __restrict__ ar_out)
{
  __shared__ __align__(16) bf16_t sBuf[TROWS * HSTR];   // X (XSTR view) / H2
  __shared__ __align__(16) bf16_t sHa[TROWS * HSTR];    // H1
  __shared__ __align__(16) bf16_t sFS[16 * HSTR];       // feat_s (rows 8..15 zero)
  __shared__ __align__(16) bf16_t sAR[16 * HSTR];       // [r(0..63)|a(64..127)] per sample
  __shared__ __align__(16) bf16_t sFB[2048];            // final B-frags [Wr1|Wa1] 128x4
  __shared__ __align__(16) float sWt[TROWS];
  __shared__ float sWs[8];

  const int tid = threadIdx.x;
  const int wid = tid >> 6, l = tid & 63;
  const int q = l >> 4, n = l & 15;
  const int cp = wid & 3, rh = wid >> 2;

  // ---- persistent register B-fragments: w1, w2 only (64 VGPRs) ----
  const bf16x8* pk = (const bf16x8*)wpack;
  bf16x8 w1f[2][4], w2f[2][4];
#pragma unroll
  for (int nt = 0; nt < 2; nt++) {
    int t = cp * 2 + nt;
#pragma unroll
    for (int s = 0; s < 4; s++) w1f[nt][s] = pk[PK_W1 + (t * 4 + s) * 64 + l];
#pragma unroll
    for (int s = 0; s < 4; s++) w2f[nt][s] = pk[PK_W2 + (t * 4 + s) * 64 + l];
  }

  float bias0[2], bias1[2], bias2[2];
#pragma unroll
  for (int nt = 0; nt < 2; nt++) {
    int c = (cp * 2 + nt) * 16 + n;
    bias0[nt] = b0g[c]; bias1[nt] = b1g[c]; bias2[nt] = b2g[c];
  }
  const float biasH = (wid < 4) ? ba0g[cp * 16 + n] : br0g[cp * 16 + n];
  const float ba1v = ba1g[0];
  const float br1v0 = br1g[0], br1v1 = br1g[1], br1v2 = br1g[2];

  // ---- one-time LDS init ----
  for (int i = tid; i < 8 * HSTR; i += 512) {
    sFS[8 * HSTR + i] = (bf16_t)0.f;    // zero rows 8..15
    sAR[8 * HSTR + i] = (bf16_t)0.f;
  }
  {  // final-head B fragments: B[k][c] = k<64 ? Wr1[k*3+c] (c<3) : Wa1[k-64] (c==3)
    int e0 = tid * 4;
    int jh = e0 & 7, ll = (e0 >> 3) & 63, s = e0 >> 9;
#pragma unroll
    for (int ii = 0; ii < 4; ii++) {
      int j = jh + ii;
      int k = s * 32 + (ll >> 4) * 8 + j;
      int cc = ll & 15;
      float v = 0.f;
      if (cc < 3 && k < 64) v = wr1g[k * 3 + cc];
      else if (cc == 3 && k >= 64) v = wa1g[k - 64];
      sFB[e0 + ii] = (bf16_t)v;
    }
  }
  __syncthreads();

  for (int tile = blockIdx.x; tile < NTILES; tile += gridDim.x) {
    const int m0 = tile * TROWS;
    // tile-dependent zero offset (tile < 2^14, so >>20 == 0): defeats LICM so
    // w0f/head-frag loads stay inside the loop (L1-hit, short register liveness)
    const bf16x8* pkt = pk + (tile >> 20);

    // ---- per-tile w0 fragments (consumed in layer 0, then regs freed) ----
    bf16x8 w0f[2][3];
#pragma unroll
    for (int nt = 0; nt < 2; nt++)
#pragma unroll
      for (int s = 0; s < 3; s++)
        w0f[nt][s] = pkt[PK_W0 + ((cp * 2 + nt) * 3 + s) * 64 + l];

    // ---- staging: thread (r = tid>>3, p = tid&7) ----
    {
      const int r = tid >> 3, p = tid & 7;
      const int m = m0 + r;
      const int idx = ind[m];
      const float4* fp = (const float4*)(map_feat + (size_t)idx * 64 + p * 8);
      float4 f0 = fp[0], f1 = fp[1];
      bf16x8 v;
      v[0] = (bf16_t)f0.x; v[1] = (bf16_t)f0.y; v[2] = (bf16_t)f0.z; v[3] = (bf16_t)f0.w;
      v[4] = (bf16_t)f1.x; v[5] = (bf16_t)f1.y; v[6] = (bf16_t)f1.z; v[7] = (bf16_t)f1.w;
      *(bf16x8*)(sBuf + r * XSTR + p * 8) = v;
      const int g = m >> 3;
      if (p < 6) {
        const int d = p >> 1;
        float o = sample_xyz[g * 3 + d] - map_xyz[idx * 3 + d];
        float s1 = __sinf(o), c1 = __cosf(o);
        float s2 = 2.f * s1 * c1, c2 = 1.f - 2.f * s1 * s1;
        float s4 = 2.f * s2 * c2, c4 = 1.f - 2.f * s2 * s2;
        float s8 = 2.f * s4 * c4, c8 = 1.f - 2.f * s4 * s4;
        bf16x4 e;
        if (p & 1) { e[0] = (bf16_t)c1; e[1] = (bf16_t)c2; e[2] = (bf16_t)c4; e[3] = (bf16_t)c8; }
        else       { e[0] = (bf16_t)s1; e[1] = (bf16_t)s2; e[2] = (bf16_t)s4; e[3] = (bf16_t)s8; }
        *(bf16x4*)(sBuf + r * XSTR + 64 + d * 8 + (p & 1) * 4) = e;
      } else if (p == 6) {
        bf16x8 z = {};
        *(bf16x8*)(sBuf + r * XSTR + 88) = z;   // pad cols 88..95
      } else {
        float ox = sample_xyz[g * 3 + 0] - map_xyz[idx * 3 + 0];
        float oy = sample_xyz[g * 3 + 1] - map_xyz[idx * 3 + 1];
        float oz = sample_xyz[g * 3 + 2] - map_xyz[idx * 3 + 2];
        sWt[r] = __expf(-10.f * sqrtf(ox * ox + oy * oy + oz * oz));
      }
    }
    __syncthreads();   // B1: X, wt ready

    if (tid < 8) {
      float ss = 0.f;
#pragma unroll
      for (int k = 0; k < 8; k++) ss += sWt[tid * 8 + k];
      sWs[tid] = ss;
    }

    // ---- layer 0: sBuf(X) -> sHa ----
    {
      f32x4 acc[2][2] = {};
#pragma unroll
      for (int g = 0; g < 2; g++) {
        const bf16_t* xb = sBuf + ((rh * 2 + g) * 16 + n) * XSTR + q * 8;
#pragma unroll
        for (int s = 0; s < 3; s++) {
          bf16x8 a = *(const bf16x8*)(xb + s * 32);
          acc[g][0] = __builtin_amdgcn_mfma_f32_16x16x32_bf16(a, w0f[0][s], acc[g][0], 0, 0, 0);
          acc[g][1] = __builtin_amdgcn_mfma_f32_16x16x32_bf16(a, w0f[1][s], acc[g][1], 0, 0, 0);
        }
      }
#pragma unroll
      for (int g = 0; g < 2; g++)
#pragma unroll
        for (int nt = 0; nt < 2; nt++)
#pragma unroll
          for (int i = 0; i < 4; i++) {
            float v = lrelu(acc[g][nt][i] + bias0[nt]);
            sHa[((rh * 2 + g) * 16 + q * 4 + i) * HSTR + (cp * 2 + nt) * 16 + n] = (bf16_t)v;
          }
    }
    __syncthreads();   // B2

    // ---- layer 1: sHa -> sBuf ----
    {
      f32x4 acc[2][2] = {};
#pragma unroll
      for (int g = 0; g < 2; g++) {
        const bf16_t* hb = sHa + ((rh * 2 + g) * 16 + n) * HSTR + q * 8;
#pragma unroll
        for (int s = 0; s < 4; s++) {
          bf16x8 a = *(const bf16x8*)(hb + s * 32);
          acc[g][0] = __builtin_amdgcn_mfma_f32_16x16x32_bf16(a, w1f[0][s], acc[g][0], 0, 0, 0);
          acc[g][1] = __builtin_amdgcn_mfma_f32_16x16x32_bf16(a, w1f[1][s], acc[g][1], 0, 0, 0);
        }
      }
#pragma unroll
      for (int g = 0; g < 2; g++)
#pragma unroll
        for (int nt = 0; nt < 2; nt++)
#pragma unroll
          for (int i = 0; i < 4; i++) {
            float v = lrelu(acc[g][nt][i] + bias1[nt]);
            sBuf[((rh * 2 + g) * 16 + q * 4 + i) * HSTR + (cp * 2 + nt) * 16 + n] = (bf16_t)v;
          }
    }
    __syncthreads();   // B3

    // ---- per-tile head fragments (consumed after B4) ----
    bf16x8 hdf[4];
#pragma unroll
    for (int s = 0; s < 4; s++)
      hdf[s] = pkt[(wid < 4 ? PK_WA : PK_WR) + ((wid & 3) * 4 + s) * 64 + l];

    // ---- layer 2 + fused K-reduce: sBuf -> regs -> sFS ----
    // row = (rh*2+g)*16 + q*4 + i  => sample j = rh*4 + g*2 + (q>>1),
    // k = (q&1)*4 + i; partner lane^16 holds complementary k-half.
    {
      f32x4 acc[2][2] = {};
#pragma unroll
      for (int g = 0; g < 2; g++) {
        const bf16_t* hb = sBuf + ((rh * 2 + g) * 16 + n) * HSTR + q * 8;
#pragma unroll
        for (int s = 0; s < 4; s++) {
          bf16x8 a = *(const bf16x8*)(hb + s * 32);
          acc[g][0] = __builtin_amdgcn_mfma_f32_16x16x32_bf16(a, w2f[0][s], acc[g][0], 0, 0, 0);
          acc[g][1] = __builtin_amdgcn_mfma_f32_16x16x32_bf16(a, w2f[1][s], acc[g][1], 0, 0, 0);
        }
      }
#pragma unroll
      for (int g = 0; g < 2; g++) {
        const int j = rh * 4 + g * 2 + (q >> 1);
        const float4 wt4 = *(const float4*)(sWt + j * 8 + 4 * (q & 1));
        const float inv = __builtin_amdgcn_rcpf(sWs[j]);
#pragma unroll
        for (int nt = 0; nt < 2; nt++) {
          float part = 0.f;
#pragma unroll
          for (int i = 0; i < 4; i++) {
            float v = lrelu(acc[g][nt][i] + bias2[nt]);
            part += ((const float*)&wt4)[i] * v;
          }
          part += __shfl_xor(part, 16);     // unconditional, full exec mask
          if (!(q & 1)) sFS[j * HSTR + (cp * 2 + nt) * 16 + n] = (bf16_t)(part * inv);
        }
      }
    }
    __syncthreads();   // B4: feat_s ready

    // ---- heads: waves 0..3 -> a-vals (cols 64..127), 4..7 -> r-vals (0..63) ----
    {
      f32x4 ha = {};
#pragma unroll
      for (int s = 0; s < 4; s++) {
        bf16x8 a = *(const bf16x8*)(sFS + n * HSTR + s * 32 + q * 8);
        ha = __builtin_amdgcn_mfma_f32_16x16x32_bf16(a, hdf[s], ha, 0, 0, 0);
      }
      if (q < 2) {   // valid sample rows 0..7
        const int base = (wid < 4) ? 64 : 0;
#pragma unroll
        for (int i = 0; i < 4; i++) {
          float v = lrelu(ha[i] + biasH);
          sAR[(q * 4 + i) * HSTR + base + (wid & 3) * 16 + n] = (bf16_t)v;
        }
      }
    }
    __syncthreads();   // B5: sAR ready

    // ---- finals: wave 0, one 16x16x32-chain MFMA (no shuffles) ----
    if (wid == 0) {
      f32x4 c = {};
#pragma unroll
      for (int s = 0; s < 4; s++) {
        bf16x8 a = *(const bf16x8*)(sAR + n * HSTR + s * 32 + q * 8);
        bf16x8 b = *(const bf16x8*)(sFB + (s * 64 + l) * 8);
        c = __builtin_amdgcn_mfma_f32_16x16x32_bf16(a, b, c, 0, 0, 0);
      }
      if (q < 2 && n < 4) {
        float bias = (n == 3) ? ba1v : ((n == 0) ? br1v0 : (n == 1) ? br1v1 : br1v2);
#pragma unroll
        for (int i = 0; i < 4; i++)
          ar_out[(size_t)(m0 / 8 + q * 4 + i) * 4 + n] = sigmoidf(c[i] + bias);
      }
    }
    // no trailing barrier: next staging writes sBuf/sWt (re-read only after
    // next B1); sAR rewritten only after next B4, by which time wave 0 has
    // finished finals (it must pass next B1..B4 too).
  }
}

// ---------------------------------------------------------------------------
// Volume rendering: one wave per ray; lane s holds sample s. Transmittance
// via shuffle-based inclusive product scan, sums via butterfly reduction.
// All cross-lane ops execute with FULL exec mask (round-2/3 lesson).
// ---------------------------------------------------------------------------
__global__ __launch_bounds__(512)
void render_kernel(const float* __restrict__ ar, const float* __restrict__ dcam,
                   float* __restrict__ out) {
  int ray = blockIdx.x * 8 + (threadIdx.x >> 6);
  int s = threadIdx.x & 63;
  float4 v = ((const float4*)ar)[ray * 64 + s];
  float alpha = v.w;
  float t = 1.f - alpha + 1e-10f;
  float p = t;
#pragma unroll
  for (int d = 1; d < 64; d <<= 1) {
    float o = __shfl_up(p, d);
    if (s >= d) p *= o;
  }
  float pm1 = __shfl_up(p, 1);                // unconditional: all lanes active
  float T = (s == 0) ? 1.f : pm1;             // exclusive product
  float bl = alpha * T;
  float dist = 1.f + 1.25f * dcam[ray * 64 + s];  // DEPTH_MIN + DEPTH_MAX*d/STEPS
  float cr = v.x * bl, cg = v.y * bl, cb = v.z * bl, cd = dist * bl, ca = bl;
#pragma unroll
  for (int d = 32; d > 0; d >>= 1) {
    cr += __shfl_xor(cr, d);
    cg += __shfl_xor(cg, d);
    cb += __shfl_xor(cb, d);
    cd += __shfl_xor(cd, d);
    ca += __shfl_xor(ca, d);
  }
  if (s == 0) {
    out[ray * 5 + 0] = cr; out[ray * 5 + 1] = cg; out[ray * 5 + 2] = cb;
    out[ray * 5 + 3] = cd; out[ray * 5 + 4] = ca;
  }
}

// ---------------------------------------------------------------------------
extern "C" void kernel_launch(void* const* d_in, const int* in_sizes, int n_in,
                              void* d_out, int out_size, void* d_ws, size_t ws_size,
                              hipStream_t stream) {
  const float* map_xyz    = (const float*)d_in[0];
  const float* map_feat   = (const float*)d_in[1];
  const int*   ind        = (const int*)d_in[2];
  const float* sample_xyz = (const float*)d_in[3];
  const float* dist_cam   = (const float*)d_in[4];
  const float* W0  = (const float*)d_in[5];
  const float* b0  = (const float*)d_in[6];
  const float* W1  = (const float*)d_in[7];
  const float* b1  = (const float*)d_in[8];
  const float* W2  = (const float*)d_in[9];
  const float* b2  = (const float*)d_in[10];
  const float* Wa0 = (const float*)d_in[11];
  const float* ba0 = (const float*)d_in[12];
  const float* Wa1 = (const float*)d_in[13];
  const float* ba1 = (const float*)d_in[14];
  const float* Wr0 = (const float*)d_in[15];
  const float* br0 = (const float*)d_in[16];
  const float* Wr1 = (const float*)d_in[17];
  const float* br1 = (const float*)d_in[18];

  bf16_t* wpack = (bf16_t*)d_ws;
  float*  ar    = (float*)((char*)d_ws + WS_AR_BYTES);

  pack_weights<<<240, 256, 0, stream>>>(W0, W1, W2, Wa0, Wr0, wpack);
  nerf_main<<<512, 512, 0, stream>>>(map_xyz, map_feat, ind, sample_xyz,
                                     b0, b1, b2, ba0, Wa1, ba1, br0, Wr1, br1,
                                     wpack, ar);
  render_kernel<<<256, 512, 0, stream>>>(ar, dist_cam, (float*)d_out);
}

// Round 7
// 401.431 us; speedup vs baseline: 1.2452x; 1.2452x over previous
//
#include <hip/hip_runtime.h>

typedef __bf16 bf16_t;
typedef __bf16 bf16x4 __attribute__((ext_vector_type(4)));
typedef __bf16 bf16x8 __attribute__((ext_vector_type(8)));
typedef float  f32x4  __attribute__((ext_vector_type(4)));

#define NPIX 2048
#define NS   64
#define NK   8
#define NSAMP (NPIX*NS)          // 131072
#define NROWS (NSAMP*NK)         // 1048576
#define TROWS 64
#define NTILES (NROWS/TROWS)     // 16384
#define XSTR 104                 // 96 cols + 8 pad (bf16), rows 16B-aligned
#define HSTR 136                 // 128 cols + 8 pad (bf16), rows 16B-aligned

// packed-weight fragment bases (in bf16x8 units) — pack layout UNCHANGED:
// the B-fragment pack of W is element-identical to the A-fragment pack of W^T.
#define PK_W0 0
#define PK_W1 1536
#define PK_W2 3584
#define PK_WA 5632
#define PK_WR 6656
#define PK_TOT 7680

#define WS_AR_BYTES 122880       // float4 per sample after packed weights

// ---------------------------------------------------------------------------
// Pack W (row-major [KD,ND] fp32), bf16:
// elem e = ((t*KS + s)*64 + l)*8 + j  holds  W[s*32 + (l>>4)*8 + j][t*16 + (l&15)]
// Interpreted as A-fragment of W^T: A[m = l&15][k = s*32+(l>>4)*8+j] = W[k][m].
// ---------------------------------------------------------------------------
__global__ void pack_weights(const float* __restrict__ W0, const float* __restrict__ W1,
                             const float* __restrict__ W2, const float* __restrict__ Wa0,
                             const float* __restrict__ Wr0, bf16_t* __restrict__ dst0) {
  int tid = blockIdx.x * blockDim.x + threadIdx.x;
  if (tid >= PK_TOT * 8) return;
  const float* src; bf16_t* dst; int e, KD, ND, KS;
  if (tid < 12288)      { src = W0;  dst = dst0;         e = tid;         KD = 88;  ND = 128; KS = 3; }
  else if (tid < 28672) { src = W1;  dst = dst0 + 12288; e = tid - 12288; KD = 128; ND = 128; KS = 4; }
  else if (tid < 45056) { src = W2;  dst = dst0 + 28672; e = tid - 28672; KD = 128; ND = 128; KS = 4; }
  else if (tid < 53248) { src = Wa0; dst = dst0 + 45056; e = tid - 45056; KD = 128; ND = 64;  KS = 4; }
  else                  { src = Wr0; dst = dst0 + 53248; e = tid - 53248; KD = 128; ND = 64;  KS = 4; }
  int j = e & 7, l = (e >> 3) & 63, f = e >> 9;
  int s = f % KS, t = f / KS;
  int row = s * 32 + (l >> 4) * 8 + j;
  int col = t * 16 + (l & 15);
  float v = (row < KD) ? src[row * ND + col] : 0.f;
  dst[e] = (bf16_t)v;
}

__device__ __forceinline__ float lrelu(float v) { return fmaxf(v, 0.1f * v); }
__device__ __forceinline__ float sigmoidf(float x) { return 1.f / (1.f + __expf(-x)); }

// ---------------------------------------------------------------------------
// T-design main kernel. Block: 512 thr (8 waves). TRANSPOSED MFMA:
// D = A·B with A = W^T fragments (registers), B = activation fragments
// (contiguous b128 from row-major [sample][k] LDS). D: col = sample (lane&15),
// row = out-col (q*4+i) -> lane holds 4 CONTIGUOUS out-cols of one sample ->
// epilogue = 1 bf16x4 store (vs 16 scalar b16). Wave w owns out-col tile w
// (16 cols) x all 4 sample-tiles: ALL weights persistent in 60 VGPRs
// (w0 3 + w1 4 + w2 4 + head 4 frags) -> 2 blocks/CU, zero per-tile reloads
// (round-6 lesson: L2 is not a safe weight home under gather thrash).
// ---------------------------------------------------------------------------
__global__ __launch_bounds__(512, 4)
void nerf_main(const float* __restrict__ map_xyz, const float* __restrict__ map_feat,
               const int* __restrict__ ind, const float* __restrict__ sample_xyz,
               const float* __restrict__ b0g, const float* __restrict__ b1g,
               const float* __restrict__ b2g, const float* __restrict__ ba0g,
               const float* __restrict__ wa1g, const float* __restrict__ ba1g,
               const float* __restrict__ br0g, const float* __restrict__ wr1g,
               const float* __restrict__ br1g, const bf16_t* __restrict__ wpack,
               float* __restrict__ ar_out)
{
  __shared__ __align__(16) bf16_t sBuf[TROWS * HSTR];   // X (XSTR view) / H2
  __shared__ __align__(16) bf16_t sHa[TROWS * HSTR];    // H1 / H3
  __shared__ __align__(16) bf16_t sFS[16 * HSTR];       // feat_s (rows 8..15 zero)
  __shared__ __align__(16) bf16_t sAR[16 * HSTR];       // [r 0..63 | a 64..127] (rows 8..15 zero)
  __shared__ __align__(16) bf16_t sFB[2048];            // finals A-frags: Wfin^T (128x4, m-padded to 16)
  __shared__ __align__(16) float sWt[TROWS];
  __shared__ float sWs[8];

  const int tid = threadIdx.x;
  const int wid = tid >> 6, l = tid & 63;
  const int q = l >> 4, n = l & 15;

  // ---- ALL weights persistent as A-fragments (60 VGPRs) ----
  const bf16x8* pk = (const bf16x8*)wpack;
  bf16x8 w0f[3], w1f[4], w2f[4], hdf[4];
#pragma unroll
  for (int s = 0; s < 3; s++) w0f[s] = pk[PK_W0 + (wid * 3 + s) * 64 + l];
#pragma unroll
  for (int s = 0; s < 4; s++) w1f[s] = pk[PK_W1 + (wid * 4 + s) * 64 + l];
#pragma unroll
  for (int s = 0; s < 4; s++) w2f[s] = pk[PK_W2 + (wid * 4 + s) * 64 + l];
#pragma unroll
  for (int s = 0; s < 4; s++)
    hdf[s] = pk[(wid < 4 ? PK_WA : PK_WR) + ((wid & 3) * 4 + s) * 64 + l];

  // ---- per-lane bias vectors: lane covers out-cols wid*16 + q*4 .. +3 ----
  const float4 b0v = *(const float4*)(b0g + wid * 16 + q * 4);
  const float4 b1v = *(const float4*)(b1g + wid * 16 + q * 4);
  const float4 b2v = *(const float4*)(b2g + wid * 16 + q * 4);
  const float4 bHv = *(const float4*)((wid < 4 ? ba0g : br0g) + (wid & 3) * 16 + q * 4);
  float4 fbv; fbv.x = br1g[0]; fbv.y = br1g[1]; fbv.z = br1g[2]; fbv.w = ba1g[0];

  // ---- one-time LDS init ----
  for (int i = tid; i < 8 * HSTR; i += 512) {
    sFS[8 * HSTR + i] = (bf16_t)0.f;
    sAR[8 * HSTR + i] = (bf16_t)0.f;
  }
  {  // finals A-frags: A[m][k] = Wfin[k][m]; m<3 -> Wr1 (k<64), m==3 -> Wa1 (k>=64)
    int e0 = tid * 4;
    int jb = e0 & 7, ll = (e0 >> 3) & 63, s = e0 >> 9;
    int m = ll & 15;
#pragma unroll
    for (int ii = 0; ii < 4; ii++) {
      int k = s * 32 + (ll >> 4) * 8 + jb + ii;
      float v = 0.f;
      if (k < 64)  { if (m < 3) v = wr1g[k * 3 + m]; }
      else         { if (m == 3) v = wa1g[k - 64]; }
      sFB[e0 + ii] = (bf16_t)v;
    }
  }
  __syncthreads();

  for (int tile = blockIdx.x; tile < NTILES; tile += gridDim.x) {
    const int m0 = tile * TROWS;

    // ---- staging: thread (r = tid>>3, p = tid&7), X row-major [sample][k] ----
    {
      const int r = tid >> 3, p = tid & 7;
      const int m = m0 + r;
      const int idx = ind[m];
      const float4* fp = (const float4*)(map_feat + (size_t)idx * 64 + p * 8);
      float4 f0 = fp[0], f1 = fp[1];
      bf16x8 v;
      v[0] = (bf16_t)f0.x; v[1] = (bf16_t)f0.y; v[2] = (bf16_t)f0.z; v[3] = (bf16_t)f0.w;
      v[4] = (bf16_t)f1.x; v[5] = (bf16_t)f1.y; v[6] = (bf16_t)f1.z; v[7] = (bf16_t)f1.w;
      *(bf16x8*)(sBuf + r * XSTR + p * 8) = v;
      const int g = m >> 3;
      if (p < 6) {
        const int d = p >> 1;
        float o = sample_xyz[g * 3 + d] - map_xyz[idx * 3 + d];
        float s1 = __sinf(o), c1 = __cosf(o);
        float s2 = 2.f * s1 * c1, c2 = 1.f - 2.f * s1 * s1;
        float s4 = 2.f * s2 * c2, c4 = 1.f - 2.f * s2 * s2;
        float s8 = 2.f * s4 * c4, c8 = 1.f - 2.f * s4 * s4;
        bf16x4 e;
        if (p & 1) { e[0] = (bf16_t)c1; e[1] = (bf16_t)c2; e[2] = (bf16_t)c4; e[3] = (bf16_t)c8; }
        else       { e[0] = (bf16_t)s1; e[1] = (bf16_t)s2; e[2] = (bf16_t)s4; e[3] = (bf16_t)s8; }
        *(bf16x4*)(sBuf + r * XSTR + 64 + d * 8 + (p & 1) * 4) = e;
      } else if (p == 6) {
        bf16x8 z = {};
        *(bf16x8*)(sBuf + r * XSTR + 88) = z;   // pad cols 88..95 (zero k-rows)
      } else {
        float ox = sample_xyz[g * 3 + 0] - map_xyz[idx * 3 + 0];
        float oy = sample_xyz[g * 3 + 1] - map_xyz[idx * 3 + 1];
        float oz = sample_xyz[g * 3 + 2] - map_xyz[idx * 3 + 2];
        sWt[r] = __expf(-10.f * sqrtf(ox * ox + oy * oy + oz * oz));
      }
    }
    __syncthreads();   // B1: X, wt ready

    if (tid < 8) {
      float ss = 0.f;
#pragma unroll
      for (int k = 0; k < 8; k++) ss += sWt[tid * 8 + k];
      sWs[tid] = ss;
    }

    // ---- layer 0 (K=96): B-frags from sBuf(X), D -> sHa ----
    {
      f32x4 acc[4] = {};
#pragma unroll
      for (int st = 0; st < 4; st++)
#pragma unroll
        for (int s = 0; s < 3; s++) {
          bf16x8 b = *(const bf16x8*)(sBuf + (st * 16 + n) * XSTR + s * 32 + q * 8);
          acc[st] = __builtin_amdgcn_mfma_f32_16x16x32_bf16(w0f[s], b, acc[st], 0, 0, 0);
        }
#pragma unroll
      for (int st = 0; st < 4; st++) {
        bf16x4 o;
        o[0] = (bf16_t)lrelu(acc[st][0] + b0v.x);
        o[1] = (bf16_t)lrelu(acc[st][1] + b0v.y);
        o[2] = (bf16_t)lrelu(acc[st][2] + b0v.z);
        o[3] = (bf16_t)lrelu(acc[st][3] + b0v.w);
        *(bf16x4*)(sHa + (st * 16 + n) * HSTR + wid * 16 + q * 4) = o;
      }
    }
    __syncthreads();   // B2: H1 ready

    // ---- layer 1: sHa -> sBuf ----
    {
      f32x4 acc[4] = {};
#pragma unroll
      for (int st = 0; st < 4; st++)
#pragma unroll
        for (int s = 0; s < 4; s++) {
          bf16x8 b = *(const bf16x8*)(sHa + (st * 16 + n) * HSTR + s * 32 + q * 8);
          acc[st] = __builtin_amdgcn_mfma_f32_16x16x32_bf16(w1f[s], b, acc[st], 0, 0, 0);
        }
#pragma unroll
      for (int st = 0; st < 4; st++) {
        bf16x4 o;
        o[0] = (bf16_t)lrelu(acc[st][0] + b1v.x);
        o[1] = (bf16_t)lrelu(acc[st][1] + b1v.y);
        o[2] = (bf16_t)lrelu(acc[st][2] + b1v.z);
        o[3] = (bf16_t)lrelu(acc[st][3] + b1v.w);
        *(bf16x4*)(sBuf + (st * 16 + n) * HSTR + wid * 16 + q * 4) = o;
      }
    }
    __syncthreads();   // B3: H2 ready

    // ---- layer 2: sBuf -> sHa (H3) ----
    {
      f32x4 acc[4] = {};
#pragma unroll
      for (int st = 0; st < 4; st++)
#pragma unroll
        for (int s = 0; s < 4; s++) {
          bf16x8 b = *(const bf16x8*)(sBuf + (st * 16 + n) * HSTR + s * 32 + q * 8);
          acc[st] = __builtin_amdgcn_mfma_f32_16x16x32_bf16(w2f[s], b, acc[st], 0, 0, 0);
        }
#pragma unroll
      for (int st = 0; st < 4; st++) {
        bf16x4 o;
        o[0] = (bf16_t)lrelu(acc[st][0] + b2v.x);
        o[1] = (bf16_t)lrelu(acc[st][1] + b2v.y);
        o[2] = (bf16_t)lrelu(acc[st][2] + b2v.z);
        o[3] = (bf16_t)lrelu(acc[st][3] + b2v.w);
        *(bf16x4*)(sHa + (st * 16 + n) * HSTR + wid * 16 + q * 4) = o;
      }
    }
    __syncthreads();   // B4: H3 ready

    // ---- K-reduce (round-4 verified scheme): feat_s -> sFS ----
    {
      int g = tid >> 6;
      int c = (tid & 63) * 2;
      float a0 = 0.f, a1 = 0.f;
#pragma unroll
      for (int k = 0; k < 8; k++) {
        float wk = sWt[g * 8 + k];
        unsigned u = *(const unsigned*)(sHa + (g * 8 + k) * HSTR + c);
        a0 += wk * __uint_as_float(u << 16);
        a1 += wk * __uint_as_float(u & 0xffff0000u);
      }
      float inv = 1.f / sWs[g];
      sFS[g * HSTR + c]     = (bf16_t)(a0 * inv);
      sFS[g * HSTR + c + 1] = (bf16_t)(a1 * inv);
    }
    __syncthreads();   // B5: feat_s ready

    // ---- heads (transposed): D[headcol][group]; store bf16x4 -> sAR ----
    {
      f32x4 ha = {};
#pragma unroll
      for (int s = 0; s < 4; s++) {
        bf16x8 b = *(const bf16x8*)(sFS + n * HSTR + s * 32 + q * 8);
        ha = __builtin_amdgcn_mfma_f32_16x16x32_bf16(hdf[s], b, ha, 0, 0, 0);
      }
      if (n < 8) {   // valid sample groups; rows 8..15 of sAR must stay zero
        const int base = (wid < 4) ? 64 : 0;    // a-vals high, r-vals low
        bf16x4 o;
        o[0] = (bf16_t)lrelu(ha[0] + bHv.x);
        o[1] = (bf16_t)lrelu(ha[1] + bHv.y);
        o[2] = (bf16_t)lrelu(ha[2] + bHv.z);
        o[3] = (bf16_t)lrelu(ha[3] + bHv.w);
        *(bf16x4*)(sAR + n * HSTR + base + (wid & 3) * 16 + q * 4) = o;
      }
    }
    __syncthreads();   // B6: sAR ready

    // ---- finals: wave 0, transposed MFMA; lane q=0 holds sample n's float4 ----
    if (wid == 0) {
      f32x4 c = {};
#pragma unroll
      for (int s = 0; s < 4; s++) {
        bf16x8 a = *(const bf16x8*)(sFB + (s * 64 + l) * 8);
        bf16x8 b = *(const bf16x8*)(sAR + n * HSTR + s * 32 + q * 8);
        c = __builtin_amdgcn_mfma_f32_16x16x32_bf16(a, b, c, 0, 0, 0);
      }
      if (q == 0 && n < 8) {   // rows q*4+i = channels 0..3, col n = sample
        float4 o;
        o.x = sigmoidf(c[0] + fbv.x);
        o.y = sigmoidf(c[1] + fbv.y);
        o.z = sigmoidf(c[2] + fbv.z);
        o.w = sigmoidf(c[3] + fbv.w);
        ((float4*)ar_out)[m0 / 8 + n] = o;
      }
    }
    // no trailing barrier: staging writes sBuf/sWt (re-read only after next B1);
    // sAR/sFS rewritten only after next B4/B5, which all threads (incl. the
    // finals wave) reach only after finishing this tile.
  }
}

// ---------------------------------------------------------------------------
// Volume rendering: one wave per ray; lane s holds sample s. All cross-lane
// ops execute with FULL exec mask (round-2/3 lesson: masked-source bpermute).
// ---------------------------------------------------------------------------
__global__ __launch_bounds__(512)
void render_kernel(const float* __restrict__ ar, const float* __restrict__ dcam,
                   float* __restrict__ out) {
  int ray = blockIdx.x * 8 + (threadIdx.x >> 6);
  int s = threadIdx.x & 63;
  float4 v = ((const float4*)ar)[ray * 64 + s];
  float alpha = v.w;
  float t = 1.f - alpha + 1e-10f;
  float p = t;
#pragma unroll
  for (int d = 1; d < 64; d <<= 1) {
    float o = __shfl_up(p, d);
    if (s >= d) p *= o;
  }
  float pm1 = __shfl_up(p, 1);                // unconditional
  float T = (s == 0) ? 1.f : pm1;             // exclusive product
  float bl = alpha * T;
  float dist = 1.f + 1.25f * dcam[ray * 64 + s];
  float cr = v.x * bl, cg = v.y * bl, cb = v.z * bl, cd = dist * bl, ca = bl;
#pragma unroll
  for (int d = 32; d > 0; d >>= 1) {
    cr += __shfl_xor(cr, d);
    cg += __shfl_xor(cg, d);
    cb += __shfl_xor(cb, d);
    cd += __shfl_xor(cd, d);
    ca += __shfl_xor(ca, d);
  }
  if (s == 0) {
    out[ray * 5 + 0] = cr; out[ray * 5 + 1] = cg; out[ray * 5 + 2] = cb;
    out[ray * 5 + 3] = cd; out[ray * 5 + 4] = ca;
  }
}

// ---------------------------------------------------------------------------
extern "C" void kernel_launch(void* const* d_in, const int* in_sizes, int n_in,
                              void* d_out, int out_size, void* d_ws, size_t ws_size,
                              hipStream_t stream) {
  const float* map_xyz    = (const float*)d_in[0];
  const float* map_feat   = (const float*)d_in[1];
  const int*   ind        = (const int*)d_in[2];
  const float* sample_xyz = (const float*)d_in[3];
  const float* dist_cam   = (const float*)d_in[4];
  const float* W0  = (const float*)d_in[5];
  const float* b0  = (const float*)d_in[6];
  const float* W1  = (const float*)d_in[7];
  const float* b1  = (const float*)d_in[8];
  const float* W2  = (const float*)d_in[9];
  const float* b2  = (const float*)d_in[10];
  const float* Wa0 = (const float*)d_in[11];
  const float* ba0 = (const float*)d_in[12];
  const float* Wa1 = (const float*)d_in[13];
  const float* ba1 = (const float*)d_in[14];
  const float* Wr0 = (const float*)d_in[15];
  const float* br0 = (const float*)d_in[16];
  const float* Wr1 = (const float*)d_in[17];
  const float* br1 = (const float*)d_in[18];

  bf16_t* wpack = (bf16_t*)d_ws;
  float*  ar    = (float*)((char*)d_ws + WS_AR_BYTES);

  pack_weights<<<240, 256, 0, stream>>>(W0, W1, W2, Wa0, Wr0, wpack);
  nerf_main<<<512, 512, 0, stream>>>(map_xyz, map_feat, ind, sample_xyz,
                                     b0, b1, b2, ba0, Wa1, ba1, br0, Wr1, br1,
                                     wpack, ar);
  render_kernel<<<256, 512, 0, stream>>>(ar, dist_cam, (float*)d_out);
}